// Round 1
// baseline (117.811 us; speedup 1.0000x reference)
//
#include <hip/hip_runtime.h>
#include <math.h>

// TopLeftPool: p[b,c,i,j] = max_{h>=i, w>=j} x[b,c,h,w]
// = reverse cummax over H then W.
// Streaming formulation per (b,c) map, bottom-up over rows:
//   p[i][:] = max(suffix_max_within_row(x[i])[:], p[i+1][:])
// One 64-lane wave per map; lane l holds columns {2l, 2l+1} as float2.
// Row suffix-max = lane-local pair max + 6-step __shfl_down suffix scan.

#define N_MAPS (16 * 256)
#define HW 128

__global__ __launch_bounds__(256) void
TopLeftPool_54357106098212_kernel(const float* __restrict__ x,
                                  float* __restrict__ out) {
    const int wave = (int)((blockIdx.x * blockDim.x + threadIdx.x) >> 6);
    const int lane = (int)(threadIdx.x & 63);
    if (wave >= N_MAPS) return;

    const size_t base = (size_t)wave * (HW * HW) + 2 * lane;
    const float* __restrict__ xm = x + base;
    float* __restrict__ om = out + base;

    float carry0 = -INFINITY, carry1 = -INFINITY;

    #pragma unroll 4
    for (int r = HW - 1; r >= 0; --r) {
        const float2 v = *reinterpret_cast<const float2*>(xm + (size_t)r * HW);
        const float a = v.x, b = v.y;

        // Inclusive suffix-max scan over lanes of the pair-max:
        // after the loop, m = max over lanes >= l of max(a,b).
        float m = fmaxf(a, b);
        #pragma unroll
        for (int off = 1; off < 64; off <<= 1) {
            const float t = __shfl_down(m, off, 64);
            m = ((lane + off) < 64) ? fmaxf(m, t) : m;
        }
        // Exclusive suffix (lanes > l); lane 63 has no successor.
        float excl = __shfl_down(m, 1, 64);
        if (lane == 63) excl = -INFINITY;

        const float s1 = fmaxf(b, excl);   // suffix max at column 2l+1
        const float s0 = fmaxf(a, s1);     // suffix max at column 2l

        carry1 = fmaxf(carry1, s1);
        carry0 = fmaxf(carry0, s0);

        float2 o;
        o.x = carry0;
        o.y = carry1;
        *reinterpret_cast<float2*>(om + (size_t)r * HW) = o;
    }
}

extern "C" void kernel_launch(void* const* d_in, const int* in_sizes, int n_in,
                              void* d_out, int out_size, void* d_ws, size_t ws_size,
                              hipStream_t stream) {
    (void)in_sizes; (void)n_in; (void)out_size; (void)d_ws; (void)ws_size;
    const float* x = (const float*)d_in[0];
    float* out = (float*)d_out;

    // 4096 maps, 1 wave each, 4 waves (256 threads) per block -> 1024 blocks.
    dim3 grid(N_MAPS / 4);
    dim3 block(256);
    hipLaunchKernelGGL(TopLeftPool_54357106098212_kernel, grid, block, 0, stream,
                       x, out);
}

// Round 2
// 112.171 us; speedup vs baseline: 1.0503x; 1.0503x over previous
//
#include <hip/hip_runtime.h>
#include <math.h>

// TopLeftPool: p[b,c,i,j] = max_{h>=i, w>=j} x[b,c,h,w]  (reverse cummax H then W)
//
// One 64-lane wave per 128x128 map, streaming bottom-up 2 rows per iteration:
//   lanes  0..31  -> row 2*pr     (group 0), lane owns cols 4*(lane&31)..+3 (float4)
//   lanes 32..63  -> row 2*pr + 1 (group 1), same column block
//
// Per-row suffix-max over W done with VALU DPP (row_shl 1/2/4/8 within 16-lane
// rows; invalid lanes keep old value = identity under max), one ds_swizzle to
// broadcast lane 16's partial across the lower 16 lanes of each 32-group, and
// one bpermute for the exclusive shift. H-direction carry is folded across the
// two wave halves with 4 parallel __shfl(lane^32) exchanges; both halves keep
// an identical running column-suffix carry.

#define N_MAPS (16 * 256)
#define W 128

// m = max(m, value from lane (i + N) within its 16-lane DPP row); out-of-row
// source lanes keep old m (identity for max).
template <int CTRL>
__device__ __forceinline__ float suffix_step(float m) {
    int t = __builtin_amdgcn_update_dpp(__float_as_int(m), __float_as_int(m),
                                        CTRL, 0xF, 0xF, false);
    return fmaxf(m, __int_as_float(t));
}

__global__ __launch_bounds__(256) void
TopLeftPool_54357106098212_kernel(const float* __restrict__ x,
                                  float* __restrict__ out) {
    const int tid  = (int)(blockIdx.x * blockDim.x + threadIdx.x);
    const int wave = tid >> 6;
    const int lane = (int)(threadIdx.x & 63);
    const int i32  = lane & 31;   // index within 32-group (column block id)
    const int g    = lane >> 5;   // 0 = upper row of pair, 1 = lower row
    if (wave >= N_MAPS) return;

    const size_t mapBase = (size_t)wave * (W * W);
    const float* __restrict__ xp = x + mapBase + (size_t)g * W + (size_t)i32 * 4;
    float* __restrict__ op = out + mapBase + (size_t)g * W + (size_t)i32 * 4;

    float c0 = -INFINITY, c1 = -INFINITY, c2 = -INFINITY, c3 = -INFINITY;

    #pragma unroll 4
    for (int pr = 63; pr >= 0; --pr) {
        const float4 v =
            *reinterpret_cast<const float4*>(xp + (size_t)pr * (2 * W));

        // Lane-local suffix over the 4 owned columns.
        const float s3 = v.w;
        const float s2 = fmaxf(v.z, s3);
        const float s1 = fmaxf(v.y, s2);
        const float s0 = fmaxf(v.x, s1);

        // Suffix-max of lane maxima across the 16-lane DPP row (VALU only).
        float m = s0;
        m = suffix_step<0x101>(m);  // row_shl:1
        m = suffix_step<0x102>(m);  // row_shl:2
        m = suffix_step<0x104>(m);  // row_shl:4
        m = suffix_step<0x108>(m);  // row_shl:8
        // m = max over lanes [i .. end of its 16-lane row]

        // Combine the two 16-lane rows of each 32-group: broadcast lane 16's
        // value (covers lanes 16..31) to everyone in the group; only the lower
        // 16 lanes fold it in.
        const float w16 = __int_as_float(__builtin_amdgcn_ds_swizzle(
            __float_as_int(m), 0x0200));  // new_lane = 16 within 32-group
        const float m32 = (i32 < 16) ? fmaxf(m, w16) : m;
        // m32 = max over lanes [i32 .. 31] of lane maxima = row suffix from col 4*i32

        // Exclusive suffix: value from lane i32+1 (row suffix from col 4*(i32+1)).
        const float bp = __shfl(m32, (lane + 1) & 63);
        const float e  = (i32 == 31) ? -INFINITY : bp;

        // Per-column row-suffix values.
        const float S0 = fmaxf(s0, e);
        const float S1 = fmaxf(s1, e);
        const float S2 = fmaxf(s2, e);
        const float S3 = fmaxf(s3, e);

        // Exchange with the other wave half (other row of the pair).
        const float t0 = __shfl(S0, lane ^ 32);
        const float t1 = __shfl(S1, lane ^ 32);
        const float t2 = __shfl(S2, lane ^ 32);
        const float t3 = __shfl(S3, lane ^ 32);

        // q = pooled value for the LOWER row of the pair (row 2pr+1) semantics:
        //   group1: q = max(S_row(2pr+1), carry)  -> its output
        //   group0: q = max(S_row(2pr),   carry)  (partial)
        const float q0 = fmaxf(S0, c0);
        const float q1 = fmaxf(S1, c1);
        const float q2 = fmaxf(S2, c2);
        const float q3 = fmaxf(S3, c3);

        // New carry = max over both rows + old carry (identical in both halves).
        c0 = fmaxf(q0, t0);
        c1 = fmaxf(q1, t1);
        c2 = fmaxf(q2, t2);
        c3 = fmaxf(q3, t3);

        float4 o;
        o.x = g ? q0 : c0;   // group0 (row 2pr): needs row below folded in = c
        o.y = g ? q1 : c1;
        o.z = g ? q2 : c2;
        o.w = g ? q3 : c3;
        *reinterpret_cast<float4*>(op + (size_t)pr * (2 * W)) = o;
    }
}

extern "C" void kernel_launch(void* const* d_in, const int* in_sizes, int n_in,
                              void* d_out, int out_size, void* d_ws, size_t ws_size,
                              hipStream_t stream) {
    (void)in_sizes; (void)n_in; (void)out_size; (void)d_ws; (void)ws_size;
    const float* x = (const float*)d_in[0];
    float* out = (float*)d_out;

    // 4096 maps, 1 wave each, 4 waves (256 threads) per block -> 1024 blocks.
    dim3 grid(N_MAPS / 4);
    dim3 block(256);
    hipLaunchKernelGGL(TopLeftPool_54357106098212_kernel, grid, block, 0, stream,
                       x, out);
}